// Round 1
// baseline (1388.368 us; speedup 1.0000x reference)
//
#include <hip/hip_runtime.h>
#include <hip/hip_bf16.h>

// GraphSAGE fwd: lin0 -> SAGEConv(mean) -> relu -> SAGEConv(mean) -> edge head.
// CSR built per call (count -> scan -> fill), gather-based mean aggregation.

#define IN_X 32
#define IN_E 64
#define HID 128
#define OUTF 64

// ---------- lin0: h0 = x @ W0 + b0   [N,32]@[32,64] ----------
__global__ __launch_bounds__(256) void k_lin0(const float* __restrict__ x,
    const float* __restrict__ W0, const float* __restrict__ b0,
    float* __restrict__ h0, int N) {
  __shared__ float sW[IN_X * IN_E];
  __shared__ float sb[IN_E];
  for (int i = threadIdx.x; i < IN_X * IN_E; i += 256) sW[i] = W0[i];
  if (threadIdx.x < IN_E) sb[threadIdx.x] = b0[threadIdx.x];
  __syncthreads();
  const int ln = threadIdx.x >> 6;   // 0..3 (node within quad)
  const int c  = threadIdx.x & 63;
  for (int q = blockIdx.x; q * 4 < N; q += gridDim.x) {
    const int node = q * 4 + ln;
    if (node >= N) continue;
    const float* xr = x + (size_t)node * IN_X;
    float acc = sb[c];
    #pragma unroll
    for (int k = 0; k < IN_X; ++k) acc += xr[k] * sW[k * IN_E + c];
    h0[(size_t)node * IN_E + c] = acc;
  }
}

// ---------- degree count ----------
__global__ void k_count(const int* __restrict__ dst, int* __restrict__ cnt, int E) {
  int e = blockIdx.x * blockDim.x + threadIdx.x;
  if (e < E) atomicAdd(&cnt[dst[e]], 1);
}

// ---------- exclusive scan (single block, 1024 threads, wave-shuffle) ----------
__global__ __launch_bounds__(1024) void k_scan(const int* __restrict__ cnt,
                                               int* __restrict__ offs, int n) {
  __shared__ int wsum[16];
  __shared__ int carry_s;
  const int tid = threadIdx.x;
  const int lane = tid & 63;
  const int wid = tid >> 6;
  if (tid == 0) carry_s = 0;
  __syncthreads();
  for (int base = 0; base < n; base += 1024) {
    const int i = base + tid;
    int v = (i < n) ? cnt[i] : 0;
    int x = v;
    #pragma unroll
    for (int s = 1; s < 64; s <<= 1) {
      int y = __shfl_up(x, s, 64);
      if (lane >= s) x += y;
    }
    if (lane == 63) wsum[wid] = x;
    __syncthreads();
    if (wid == 0) {
      int w = (lane < 16) ? wsum[lane] : 0;
      #pragma unroll
      for (int s = 1; s < 16; s <<= 1) {
        int y = __shfl_up(w, s, 64);
        if (lane >= s) w += y;
      }
      if (lane < 16) wsum[lane] = w;
    }
    __syncthreads();
    const int waveoff = (wid == 0) ? 0 : wsum[wid - 1];
    const int carry = carry_s;
    if (i < n) offs[i] = carry + waveoff + (x - v);
    __syncthreads();
    if (tid == 0) carry_s = carry + wsum[15];
    __syncthreads();
  }
  if (tid == 0) offs[n] = carry_s;
}

// ---------- CSR fill ----------
__global__ void k_fill(const int* __restrict__ src, const int* __restrict__ dst,
                       const int* __restrict__ offs, int* __restrict__ fillpos,
                       int* __restrict__ csr, int E) {
  int e = blockIdx.x * blockDim.x + threadIdx.x;
  if (e < E) {
    int d = dst[e];
    int p = atomicAdd(&fillpos[d], 1);
    csr[offs[d] + p] = src[e];
  }
}

// ---------- mean aggregation, 64 features (one wave per node) ----------
__global__ __launch_bounds__(256) void k_aggr64(const float* __restrict__ feat,
    const int* __restrict__ csr, const int* __restrict__ offs,
    float* __restrict__ aggr, int N) {
  int node = blockIdx.x * 4 + (threadIdx.x >> 6);
  int f = threadIdx.x & 63;
  if (node >= N) return;
  int s0 = offs[node], s1 = offs[node + 1];
  float acc = 0.f;
  for (int j = s0; j < s1; ++j)
    acc += feat[(size_t)csr[j] * IN_E + f];
  aggr[(size_t)node * IN_E + f] = acc / fmaxf((float)(s1 - s0), 1.f);
}

// ---------- mean aggregation, 128 features (two waves per node) ----------
__global__ __launch_bounds__(256) void k_aggr128(const float* __restrict__ feat,
    const int* __restrict__ csr, const int* __restrict__ offs,
    float* __restrict__ aggr, int N) {
  int node = blockIdx.x * 2 + (threadIdx.x >> 7);
  int f = threadIdx.x & 127;
  if (node >= N) return;
  int s0 = offs[node], s1 = offs[node + 1];
  float acc = 0.f;
  for (int j = s0; j < s1; ++j)
    acc += feat[(size_t)csr[j] * HID + f];
  aggr[(size_t)node * HID + f] = acc / fmaxf((float)(s1 - s0), 1.f);
}

// ---------- lin1: h1 = relu(aggr1 @ W1l + b1l + h0 @ W1r)  [N,64]->[N,128] ----------
__global__ __launch_bounds__(256) void k_lin1(const float* __restrict__ aggr,
    const float* __restrict__ h0, const float* __restrict__ W1l,
    const float* __restrict__ W1r, const float* __restrict__ b1l,
    float* __restrict__ h1, int N) {
  __shared__ float sWl[IN_E * HID];
  __shared__ float sWr[IN_E * HID];
  for (int i = threadIdx.x; i < IN_E * HID; i += 256) { sWl[i] = W1l[i]; sWr[i] = W1r[i]; }
  __syncthreads();
  const int ln = threadIdx.x >> 7;   // 0..1
  const int c  = threadIdx.x & 127;
  const float bias = b1l[c];
  for (int pair = blockIdx.x; pair * 2 < N; pair += gridDim.x) {
    const int node = pair * 2 + ln;
    if (node >= N) continue;
    const float* ra = aggr + (size_t)node * IN_E;
    const float* rh = h0 + (size_t)node * IN_E;
    float acc = bias;
    #pragma unroll
    for (int k = 0; k < IN_E; ++k)
      acc += ra[k] * sWl[k * HID + c] + rh[k] * sWr[k * HID + c];
    h1[(size_t)node * HID + c] = fmaxf(acc, 0.f);
  }
}

// ---------- lin2: h2 = aggr2 @ W2l + b2l + h1 @ W2r   [N,128]->[N,64] ----------
__global__ __launch_bounds__(256) void k_lin2(const float* __restrict__ aggr,
    const float* __restrict__ h1, const float* __restrict__ W2l,
    const float* __restrict__ W2r, const float* __restrict__ b2l,
    float* __restrict__ h2, int N) {
  __shared__ float sWl[HID * OUTF];
  __shared__ float sWr[HID * OUTF];
  for (int i = threadIdx.x; i < HID * OUTF; i += 256) { sWl[i] = W2l[i]; sWr[i] = W2r[i]; }
  __syncthreads();
  const int ln = threadIdx.x >> 6;   // 0..3
  const int c  = threadIdx.x & 63;
  const float bias = b2l[c];
  for (int q = blockIdx.x; q * 4 < N; q += gridDim.x) {
    const int node = q * 4 + ln;
    if (node >= N) continue;
    const float* ra = aggr + (size_t)node * HID;
    const float* rh = h1 + (size_t)node * HID;
    float acc = bias;
    #pragma unroll
    for (int k = 0; k < HID; ++k)
      acc += ra[k] * sWl[k * OUTF + c] + rh[k] * sWr[k * OUTF + c];
    h2[(size_t)node * OUTF + c] = acc;
  }
}

// ---------- edge head: raw = [h2[s], h2[d]] @ Wp + bp; sigmoid ----------
__global__ __launch_bounds__(256) void k_head(const float* __restrict__ h2,
    const int* __restrict__ srcI, const int* __restrict__ dstI,
    const float* __restrict__ Wp, const float* __restrict__ bp,
    float* __restrict__ out, int E) {
  __shared__ float sW[2 * OUTF];
  if (threadIdx.x < 2 * OUTF) sW[threadIdx.x] = Wp[threadIdx.x];
  __syncthreads();
  int e = blockIdx.x * blockDim.x + threadIdx.x;
  if (e >= E) return;
  const float bias = bp[0];
  int s = srcI[e], d = dstI[e];
  const float4* hs = (const float4*)(h2 + (size_t)s * OUTF);
  const float4* hd = (const float4*)(h2 + (size_t)d * OUTF);
  float acc = bias;
  #pragma unroll
  for (int q = 0; q < 16; ++q) {
    float4 a = hs[q];
    acc += a.x * sW[4 * q] + a.y * sW[4 * q + 1] + a.z * sW[4 * q + 2] + a.w * sW[4 * q + 3];
  }
  #pragma unroll
  for (int q = 0; q < 16; ++q) {
    float4 b = hd[q];
    acc += b.x * sW[64 + 4 * q] + b.y * sW[64 + 4 * q + 1] + b.z * sW[64 + 4 * q + 2] + b.w * sW[64 + 4 * q + 3];
  }
  out[e] = acc;
  out[(size_t)E + e] = 1.f / (1.f + expf(-acc));
}

extern "C" void kernel_launch(void* const* d_in, const int* in_sizes, int n_in,
                              void* d_out, int out_size, void* d_ws, size_t ws_size,
                              hipStream_t stream) {
  const float* x   = (const float*)d_in[0];
  const int*   ei  = (const int*)d_in[1];
  const float* W0  = (const float*)d_in[2];
  const float* b0  = (const float*)d_in[3];
  const float* W1l = (const float*)d_in[4];
  const float* b1l = (const float*)d_in[5];
  const float* W1r = (const float*)d_in[6];
  const float* W2l = (const float*)d_in[7];
  const float* b2l = (const float*)d_in[8];
  const float* W2r = (const float*)d_in[9];
  const float* Wp  = (const float*)d_in[10];
  const float* bp  = (const float*)d_in[11];

  const int N = in_sizes[0] / IN_X;
  const int E = in_sizes[1] / 2;
  const int* srcI = ei;
  const int* dstI = ei + E;
  float* out = (float*)d_out;

  // workspace layout (floats): fA [N*64] | fB [N*64] | h1 [N*128] | h2 [N*64] | ints
  // h0 lives in fA; aggr1 in fB; aggr2 reuses fA..fB as contiguous N*128.
  float* fA = (float*)d_ws;
  float* fB = fA + (size_t)N * 64;
  float* h1 = fB + (size_t)N * 64;
  float* h2 = h1 + (size_t)N * 128;
  int* cnt     = (int*)(h2 + (size_t)N * 64);
  int* offs    = cnt + N;
  int* fillpos = offs + N + 1;
  int* csr     = fillpos + N;

  hipMemsetAsync(cnt, 0, sizeof(int) * (size_t)N, stream);
  hipMemsetAsync(fillpos, 0, sizeof(int) * (size_t)N, stream);

  // h0 = lin0(x)
  k_lin0<<<2048, 256, 0, stream>>>(x, W0, b0, fA, N);
  // CSR build
  k_count<<<(E + 255) / 256, 256, 0, stream>>>(dstI, cnt, E);
  k_scan<<<1, 1024, 0, stream>>>(cnt, offs, N);
  k_fill<<<(E + 255) / 256, 256, 0, stream>>>(srcI, dstI, offs, fillpos, csr, E);
  // conv1
  k_aggr64<<<(N + 3) / 4, 256, 0, stream>>>(fA, csr, offs, fB, N);
  k_lin1<<<512, 256, 0, stream>>>(fB, fA, W1l, W1r, b1l, h1, N);
  // conv2 (aggr2 overwrites fA..fB region, h0/aggr1 dead now)
  k_aggr128<<<(N + 1) / 2, 256, 0, stream>>>(h1, csr, offs, fA, N);
  k_lin2<<<512, 256, 0, stream>>>(fA, h1, W2l, W2r, b2l, h2, N);
  // edge head
  k_head<<<(E + 255) / 256, 256, 0, stream>>>(h2, srcI, dstI, Wp, bp, out, E);
}

// Round 2
// 846.499 us; speedup vs baseline: 1.6401x; 1.6401x over previous
//
#include <hip/hip_runtime.h>
#include <hip/hip_bf16.h>
#include <hip/hip_fp16.h>

// GraphSAGE fwd: lin0 -> SAGEConv(mean) -> relu -> SAGEConv(mean) -> edge head.
// CSR built per call (count -> scan -> fill), gather-based mean aggregation.
// Intermediates (h0, aggr1, h1, aggr2, h2) stored fp16, accumulation in f32:
// halves the random-gather bytes that dominate (aggr + head kernels).

#define IN_X 32
#define IN_E 64
#define HID 128
#define OUTF 64

// ---------- lin0: h0 = x @ W0 + b0   [N,32]@[32,64] -> fp16 ----------
__global__ __launch_bounds__(256) void k_lin0(const float* __restrict__ x,
    const float* __restrict__ W0, const float* __restrict__ b0,
    __half* __restrict__ h0, int N) {
  __shared__ float sW[IN_X * IN_E];
  __shared__ float sb[IN_E];
  for (int i = threadIdx.x; i < IN_X * IN_E; i += 256) sW[i] = W0[i];
  if (threadIdx.x < IN_E) sb[threadIdx.x] = b0[threadIdx.x];
  __syncthreads();
  const int ln = threadIdx.x >> 6;   // 0..3 (node within quad)
  const int c  = threadIdx.x & 63;
  for (int q = blockIdx.x; q * 4 < N; q += gridDim.x) {
    const int node = q * 4 + ln;
    if (node >= N) continue;
    const float* xr = x + (size_t)node * IN_X;
    float acc = sb[c];
    #pragma unroll
    for (int k = 0; k < IN_X; ++k) acc += xr[k] * sW[k * IN_E + c];
    h0[(size_t)node * IN_E + c] = __float2half(acc);
  }
}

// ---------- degree count ----------
__global__ void k_count(const int* __restrict__ dst, int* __restrict__ cnt, int E) {
  int e = blockIdx.x * blockDim.x + threadIdx.x;
  if (e < E) atomicAdd(&cnt[dst[e]], 1);
}

// ---------- exclusive scan (single block, 1024 threads, wave-shuffle) ----------
__global__ __launch_bounds__(1024) void k_scan(const int* __restrict__ cnt,
                                               int* __restrict__ offs, int n) {
  __shared__ int wsum[16];
  __shared__ int carry_s;
  const int tid = threadIdx.x;
  const int lane = tid & 63;
  const int wid = tid >> 6;
  if (tid == 0) carry_s = 0;
  __syncthreads();
  for (int base = 0; base < n; base += 1024) {
    const int i = base + tid;
    int v = (i < n) ? cnt[i] : 0;
    int x = v;
    #pragma unroll
    for (int s = 1; s < 64; s <<= 1) {
      int y = __shfl_up(x, s, 64);
      if (lane >= s) x += y;
    }
    if (lane == 63) wsum[wid] = x;
    __syncthreads();
    if (wid == 0) {
      int w = (lane < 16) ? wsum[lane] : 0;
      #pragma unroll
      for (int s = 1; s < 16; s <<= 1) {
        int y = __shfl_up(w, s, 64);
        if (lane >= s) w += y;
      }
      if (lane < 16) wsum[lane] = w;
    }
    __syncthreads();
    const int waveoff = (wid == 0) ? 0 : wsum[wid - 1];
    const int carry = carry_s;
    if (i < n) offs[i] = carry + waveoff + (x - v);
    __syncthreads();
    if (tid == 0) carry_s = carry + wsum[15];
    __syncthreads();
  }
  if (tid == 0) offs[n] = carry_s;
}

// ---------- CSR fill ----------
__global__ void k_fill(const int* __restrict__ src, const int* __restrict__ dst,
                       const int* __restrict__ offs, int* __restrict__ fillpos,
                       int* __restrict__ csr, int E) {
  int e = blockIdx.x * blockDim.x + threadIdx.x;
  if (e < E) {
    int d = dst[e];
    int p = atomicAdd(&fillpos[d], 1);
    csr[offs[d] + p] = src[e];
  }
}

__device__ __forceinline__ float2 h2f2(uint v) {
  __half2 h = *reinterpret_cast<__half2*>(&v);
  return __half22float2(h);
}

// ---------- mean aggregation, 64 fp16 features (one wave per node) ----------
// Row = 128B. Lanes 0-31 handle even-pair rows, 32-63 odd; combine via shfl_xor.
__global__ __launch_bounds__(256) void k_aggr64h(const __half* __restrict__ feat,
    const int* __restrict__ csr, const int* __restrict__ offs,
    __half* __restrict__ aggr, int N) {
  int node = blockIdx.x * 4 + (threadIdx.x >> 6);
  if (node >= N) return;
  const int lane = threadIdx.x & 63;
  const int h = lane >> 5;       // which row of the pair
  const int c = lane & 31;       // half2 index within row (32 * 4B = 128B)
  int s0 = offs[node], s1 = offs[node + 1];
  float2 acc = make_float2(0.f, 0.f);
  int j = s0;
  for (; j + 4 <= s1; j += 4) {
    int r0 = csr[j + h];
    int r1 = csr[j + 2 + h];
    uint v0 = ((const uint*)(feat + (size_t)r0 * IN_E))[c];
    uint v1 = ((const uint*)(feat + (size_t)r1 * IN_E))[c];
    float2 f0 = h2f2(v0), f1 = h2f2(v1);
    acc.x += f0.x + f1.x; acc.y += f0.y + f1.y;
  }
  for (; j + 2 <= s1; j += 2) {
    int r = csr[j + h];
    uint v = ((const uint*)(feat + (size_t)r * IN_E))[c];
    float2 f = h2f2(v);
    acc.x += f.x; acc.y += f.y;
  }
  if (j < s1 && h == 0) {
    int r = csr[j];
    uint v = ((const uint*)(feat + (size_t)r * IN_E))[c];
    float2 f = h2f2(v);
    acc.x += f.x; acc.y += f.y;
  }
  acc.x += __shfl_xor(acc.x, 32, 64);
  acc.y += __shfl_xor(acc.y, 32, 64);
  if (h == 0) {
    float inv = 1.f / fmaxf((float)(s1 - s0), 1.f);
    __half2 o = __floats2half2_rn(acc.x * inv, acc.y * inv);
    ((uint*)(aggr + (size_t)node * IN_E))[c] = *reinterpret_cast<uint*>(&o);
  }
}

// ---------- mean aggregation, 128 fp16 features (one wave per node) ----------
// Row = 256B = 64 lanes x half2. 4 independent row loads in flight.
__global__ __launch_bounds__(256) void k_aggr128h(const __half* __restrict__ feat,
    const int* __restrict__ csr, const int* __restrict__ offs,
    __half* __restrict__ aggr, int N) {
  int node = blockIdx.x * 4 + (threadIdx.x >> 6);
  if (node >= N) return;
  const int c = threadIdx.x & 63;  // half2 index (64 * 4B = 256B)
  int s0 = offs[node], s1 = offs[node + 1];
  float2 acc = make_float2(0.f, 0.f);
  int j = s0;
  for (; j + 4 <= s1; j += 4) {
    int r0 = csr[j], r1 = csr[j + 1], r2 = csr[j + 2], r3 = csr[j + 3];
    uint v0 = ((const uint*)(feat + (size_t)r0 * HID))[c];
    uint v1 = ((const uint*)(feat + (size_t)r1 * HID))[c];
    uint v2 = ((const uint*)(feat + (size_t)r2 * HID))[c];
    uint v3 = ((const uint*)(feat + (size_t)r3 * HID))[c];
    float2 f0 = h2f2(v0), f1 = h2f2(v1), f2 = h2f2(v2), f3 = h2f2(v3);
    acc.x += (f0.x + f1.x) + (f2.x + f3.x);
    acc.y += (f0.y + f1.y) + (f2.y + f3.y);
  }
  for (; j < s1; ++j) {
    uint v = ((const uint*)(feat + (size_t)csr[j] * HID))[c];
    float2 f = h2f2(v);
    acc.x += f.x; acc.y += f.y;
  }
  float inv = 1.f / fmaxf((float)(s1 - s0), 1.f);
  __half2 o = __floats2half2_rn(acc.x * inv, acc.y * inv);
  ((uint*)(aggr + (size_t)node * HID))[c] = *reinterpret_cast<uint*>(&o);
}

// ---------- lin1: h1 = relu(aggr1 @ W1l + b1l + h0 @ W1r)  [N,64]->[N,128] ----------
__global__ __launch_bounds__(256) void k_lin1(const __half* __restrict__ aggr,
    const __half* __restrict__ h0, const float* __restrict__ W1l,
    const float* __restrict__ W1r, const float* __restrict__ b1l,
    __half* __restrict__ h1, int N) {
  __shared__ float sWl[IN_E * HID];
  __shared__ float sWr[IN_E * HID];
  for (int i = threadIdx.x; i < IN_E * HID; i += 256) { sWl[i] = W1l[i]; sWr[i] = W1r[i]; }
  __syncthreads();
  const int ln = threadIdx.x >> 7;   // 0..1
  const int c  = threadIdx.x & 127;
  const float bias = b1l[c];
  for (int pair = blockIdx.x; pair * 2 < N; pair += gridDim.x) {
    const int node = pair * 2 + ln;
    if (node >= N) continue;
    const uint* ra = (const uint*)(aggr + (size_t)node * IN_E);
    const uint* rh = (const uint*)(h0 + (size_t)node * IN_E);
    float acc = bias;
    #pragma unroll
    for (int k2 = 0; k2 < IN_E / 2; ++k2) {
      float2 a = h2f2(ra[k2]);
      float2 hv = h2f2(rh[k2]);
      acc += a.x * sWl[(2 * k2) * HID + c] + a.y * sWl[(2 * k2 + 1) * HID + c]
           + hv.x * sWr[(2 * k2) * HID + c] + hv.y * sWr[(2 * k2 + 1) * HID + c];
    }
    h1[(size_t)node * HID + c] = __float2half(fmaxf(acc, 0.f));
  }
}

// ---------- lin2: h2 = aggr2 @ W2l + b2l + h1 @ W2r   [N,128]->[N,64] ----------
__global__ __launch_bounds__(256) void k_lin2(const __half* __restrict__ aggr,
    const __half* __restrict__ h1, const float* __restrict__ W2l,
    const float* __restrict__ W2r, const float* __restrict__ b2l,
    __half* __restrict__ h2, int N) {
  __shared__ float sWl[HID * OUTF];
  __shared__ float sWr[HID * OUTF];
  for (int i = threadIdx.x; i < HID * OUTF; i += 256) { sWl[i] = W2l[i]; sWr[i] = W2r[i]; }
  __syncthreads();
  const int ln = threadIdx.x >> 6;   // 0..3
  const int c  = threadIdx.x & 63;
  const float bias = b2l[c];
  for (int q = blockIdx.x; q * 4 < N; q += gridDim.x) {
    const int node = q * 4 + ln;
    if (node >= N) continue;
    const uint* ra = (const uint*)(aggr + (size_t)node * HID);
    const uint* rh = (const uint*)(h1 + (size_t)node * HID);
    float acc = bias;
    #pragma unroll
    for (int k2 = 0; k2 < HID / 2; ++k2) {
      float2 a = h2f2(ra[k2]);
      float2 hv = h2f2(rh[k2]);
      acc += a.x * sWl[(2 * k2) * OUTF + c] + a.y * sWl[(2 * k2 + 1) * OUTF + c]
           + hv.x * sWr[(2 * k2) * OUTF + c] + hv.y * sWr[(2 * k2 + 1) * OUTF + c];
    }
    h2[(size_t)node * OUTF + c] = __float2half(acc);
  }
}

__device__ __forceinline__ float dot8(uint4 v, const float* __restrict__ w) {
  float2 a = h2f2(v.x), b = h2f2(v.y), cc = h2f2(v.z), d = h2f2(v.w);
  return a.x * w[0] + a.y * w[1] + b.x * w[2] + b.y * w[3]
       + cc.x * w[4] + cc.y * w[5] + d.x * w[6] + d.y * w[7];
}

// ---------- edge head: raw = [h2[s], h2[d]] @ Wp + bp; sigmoid ----------
__global__ __launch_bounds__(256) void k_head(const __half* __restrict__ h2,
    const int* __restrict__ srcI, const int* __restrict__ dstI,
    const float* __restrict__ Wp, const float* __restrict__ bp,
    float* __restrict__ out, int E) {
  __shared__ float sW[2 * OUTF];
  if (threadIdx.x < 2 * OUTF) sW[threadIdx.x] = Wp[threadIdx.x];
  __syncthreads();
  int e = blockIdx.x * blockDim.x + threadIdx.x;
  if (e >= E) return;
  const float bias = bp[0];
  int s = srcI[e], d = dstI[e];
  const uint4* hs = (const uint4*)(h2 + (size_t)s * OUTF);  // 8 x uint4 per row
  const uint4* hd = (const uint4*)(h2 + (size_t)d * OUTF);
  float acc = bias;
  #pragma unroll
  for (int q = 0; q < 8; ++q) acc += dot8(hs[q], sW + 8 * q);
  #pragma unroll
  for (int q = 0; q < 8; ++q) acc += dot8(hd[q], sW + OUTF + 8 * q);
  out[e] = acc;
  out[(size_t)E + e] = 1.f / (1.f + expf(-acc));
}

extern "C" void kernel_launch(void* const* d_in, const int* in_sizes, int n_in,
                              void* d_out, int out_size, void* d_ws, size_t ws_size,
                              hipStream_t stream) {
  const float* x   = (const float*)d_in[0];
  const int*   ei  = (const int*)d_in[1];
  const float* W0  = (const float*)d_in[2];
  const float* b0  = (const float*)d_in[3];
  const float* W1l = (const float*)d_in[4];
  const float* b1l = (const float*)d_in[5];
  const float* W1r = (const float*)d_in[6];
  const float* W2l = (const float*)d_in[7];
  const float* b2l = (const float*)d_in[8];
  const float* W2r = (const float*)d_in[9];
  const float* Wp  = (const float*)d_in[10];
  const float* bp  = (const float*)d_in[11];

  const int N = in_sizes[0] / IN_X;
  const int E = in_sizes[1] / 2;
  const int* srcI = ei;
  const int* dstI = ei + E;
  float* out = (float*)d_out;

  // workspace layout: fp16 arrays then ints
  __half* h0  = (__half*)d_ws;
  __half* ag1 = h0 + (size_t)N * IN_E;
  __half* h1  = ag1 + (size_t)N * IN_E;
  __half* ag2 = h1 + (size_t)N * HID;
  __half* h2  = ag2 + (size_t)N * HID;
  int* cnt     = (int*)(h2 + (size_t)N * OUTF);
  int* offs    = cnt + N;
  int* fillpos = offs + N + 1;
  int* csr     = fillpos + N;

  hipMemsetAsync(cnt, 0, sizeof(int) * (size_t)N, stream);
  hipMemsetAsync(fillpos, 0, sizeof(int) * (size_t)N, stream);

  // h0 = lin0(x)
  k_lin0<<<2048, 256, 0, stream>>>(x, W0, b0, h0, N);
  // CSR build
  k_count<<<(E + 255) / 256, 256, 0, stream>>>(dstI, cnt, E);
  k_scan<<<1, 1024, 0, stream>>>(cnt, offs, N);
  k_fill<<<(E + 255) / 256, 256, 0, stream>>>(srcI, dstI, offs, fillpos, csr, E);
  // conv1
  k_aggr64h<<<(N + 3) / 4, 256, 0, stream>>>(h0, csr, offs, ag1, N);
  k_lin1<<<512, 256, 0, stream>>>(ag1, h0, W1l, W1r, b1l, h1, N);
  // conv2
  k_aggr128h<<<(N + 3) / 4, 256, 0, stream>>>(h1, csr, offs, ag2, N);
  k_lin2<<<512, 256, 0, stream>>>(ag2, h1, W2l, W2r, b2l, h2, N);
  // edge head
  k_head<<<(E + 255) / 256, 256, 0, stream>>>(h2, srcI, dstI, Wp, bp, out, E);
}

// Round 3
// 571.762 us; speedup vs baseline: 2.4282x; 1.4805x over previous
//
#include <hip/hip_runtime.h>
#include <hip/hip_bf16.h>
#include <hip/hip_fp16.h>

// GraphSAGE fwd: lin0 -> SAGEConv(mean) -> relu -> SAGEConv(mean) -> edge head.
// CSR built per call; gather-based mean aggregation; fp16 intermediates.
// lin1/lin2 via v_mfma_f32_16x16x32_f16 with register-resident weights.
// Edge head is separable: raw = gs[src] + gd[dst] + bp.

#define IN_X 32
#define IN_E 64
#define HID 128
#define OUTF 64

typedef _Float16 f16x8 __attribute__((ext_vector_type(8)));
typedef float f32x4 __attribute__((ext_vector_type(4)));

// ---------- lin0: h0 = x @ W0 + b0   [N,32]@[32,64] -> fp16 ----------
__global__ __launch_bounds__(256) void k_lin0(const float* __restrict__ x,
    const float* __restrict__ W0, const float* __restrict__ b0,
    __half* __restrict__ h0, int N) {
  __shared__ float sW[IN_X * IN_E];
  __shared__ float sb[IN_E];
  for (int i = threadIdx.x; i < IN_X * IN_E; i += 256) sW[i] = W0[i];
  if (threadIdx.x < IN_E) sb[threadIdx.x] = b0[threadIdx.x];
  __syncthreads();
  const int ln = threadIdx.x >> 6;
  const int c  = threadIdx.x & 63;
  for (int q = blockIdx.x; q * 4 < N; q += gridDim.x) {
    const int node = q * 4 + ln;
    if (node >= N) continue;
    const float* xr = x + (size_t)node * IN_X;
    float acc = sb[c];
    #pragma unroll
    for (int k = 0; k < IN_X; ++k) acc += xr[k] * sW[k * IN_E + c];
    h0[(size_t)node * IN_E + c] = __float2half(acc);
  }
}

// ---------- weight prep: f32 [K][C] -> fp16 transposed [C][K] ----------
__global__ void k_prepw(const float* __restrict__ W1l, const float* __restrict__ W1r,
                        const float* __restrict__ W2l, const float* __restrict__ W2r,
                        __half* __restrict__ W1lT, __half* __restrict__ W1rT,
                        __half* __restrict__ W2lT, __half* __restrict__ W2rT) {
  int i = blockIdx.x * 256 + threadIdx.x;
  if (i < IN_E * HID) {  // W1: [64][128] -> [128][64]
    int k = i >> 7, c = i & 127;
    W1lT[c * IN_E + k] = __float2half(W1l[i]);
    W1rT[c * IN_E + k] = __float2half(W1r[i]);
  }
  if (i < HID * OUTF) {  // W2: [128][64] -> [64][128]
    int k = i >> 6, c = i & 63;
    W2lT[c * HID + k] = __float2half(W2l[i]);
    W2rT[c * HID + k] = __float2half(W2r[i]);
  }
}

// ---------- degree count ----------
__global__ void k_count(const int* __restrict__ dst, int* __restrict__ cnt, int E) {
  int e = blockIdx.x * blockDim.x + threadIdx.x;
  if (e < E) atomicAdd(&cnt[dst[e]], 1);
}

// ---------- exclusive scan (single block, 1024 threads, wave-shuffle) ----------
__global__ __launch_bounds__(1024) void k_scan(const int* __restrict__ cnt,
                                               int* __restrict__ offs, int n) {
  __shared__ int wsum[16];
  __shared__ int carry_s;
  const int tid = threadIdx.x;
  const int lane = tid & 63;
  const int wid = tid >> 6;
  if (tid == 0) carry_s = 0;
  __syncthreads();
  for (int base = 0; base < n; base += 1024) {
    const int i = base + tid;
    int v = (i < n) ? cnt[i] : 0;
    int x = v;
    #pragma unroll
    for (int s = 1; s < 64; s <<= 1) {
      int y = __shfl_up(x, s, 64);
      if (lane >= s) x += y;
    }
    if (lane == 63) wsum[wid] = x;
    __syncthreads();
    if (wid == 0) {
      int w = (lane < 16) ? wsum[lane] : 0;
      #pragma unroll
      for (int s = 1; s < 16; s <<= 1) {
        int y = __shfl_up(w, s, 64);
        if (lane >= s) w += y;
      }
      if (lane < 16) wsum[lane] = w;
    }
    __syncthreads();
    const int waveoff = (wid == 0) ? 0 : wsum[wid - 1];
    const int carry = carry_s;
    if (i < n) offs[i] = carry + waveoff + (x - v);
    __syncthreads();
    if (tid == 0) carry_s = carry + wsum[15];
    __syncthreads();
  }
  if (tid == 0) offs[n] = carry_s;
}

// ---------- CSR fill ----------
__global__ void k_fill(const int* __restrict__ src, const int* __restrict__ dst,
                       const int* __restrict__ offs, int* __restrict__ fillpos,
                       int* __restrict__ csr, int E) {
  int e = blockIdx.x * blockDim.x + threadIdx.x;
  if (e < E) {
    int d = dst[e];
    int p = atomicAdd(&fillpos[d], 1);
    csr[offs[d] + p] = src[e];
  }
}

__device__ __forceinline__ float2 h2f2(uint v) {
  __half2 h = *reinterpret_cast<__half2*>(&v);
  return __half22float2(h);
}

// ---------- mean aggregation, 64 fp16 features (one wave per node) ----------
__global__ __launch_bounds__(256) void k_aggr64h(const __half* __restrict__ feat,
    const int* __restrict__ csr, const int* __restrict__ offs,
    __half* __restrict__ aggr, int N) {
  int node = blockIdx.x * 4 + (threadIdx.x >> 6);
  if (node >= N) return;
  const int lane = threadIdx.x & 63;
  const int h = lane >> 5;
  const int c = lane & 31;
  int s0 = offs[node], s1 = offs[node + 1];
  float2 acc = make_float2(0.f, 0.f);
  int j = s0;
  for (; j + 4 <= s1; j += 4) {
    int r0 = csr[j + h];
    int r1 = csr[j + 2 + h];
    uint v0 = ((const uint*)(feat + (size_t)r0 * IN_E))[c];
    uint v1 = ((const uint*)(feat + (size_t)r1 * IN_E))[c];
    float2 f0 = h2f2(v0), f1 = h2f2(v1);
    acc.x += f0.x + f1.x; acc.y += f0.y + f1.y;
  }
  for (; j + 2 <= s1; j += 2) {
    int r = csr[j + h];
    uint v = ((const uint*)(feat + (size_t)r * IN_E))[c];
    float2 f = h2f2(v);
    acc.x += f.x; acc.y += f.y;
  }
  if (j < s1 && h == 0) {
    int r = csr[j];
    uint v = ((const uint*)(feat + (size_t)r * IN_E))[c];
    float2 f = h2f2(v);
    acc.x += f.x; acc.y += f.y;
  }
  acc.x += __shfl_xor(acc.x, 32, 64);
  acc.y += __shfl_xor(acc.y, 32, 64);
  if (h == 0) {
    float inv = 1.f / fmaxf((float)(s1 - s0), 1.f);
    __half2 o = __floats2half2_rn(acc.x * inv, acc.y * inv);
    ((uint*)(aggr + (size_t)node * IN_E))[c] = *reinterpret_cast<uint*>(&o);
  }
}

// ---------- mean aggregation, 128 fp16 features (one wave per node) ----------
__global__ __launch_bounds__(256) void k_aggr128h(const __half* __restrict__ feat,
    const int* __restrict__ csr, const int* __restrict__ offs,
    __half* __restrict__ aggr, int N) {
  int node = blockIdx.x * 4 + (threadIdx.x >> 6);
  if (node >= N) return;
  const int c = threadIdx.x & 63;
  int s0 = offs[node], s1 = offs[node + 1];
  float2 acc = make_float2(0.f, 0.f);
  int j = s0;
  for (; j + 4 <= s1; j += 4) {
    int r0 = csr[j], r1 = csr[j + 1], r2 = csr[j + 2], r3 = csr[j + 3];
    uint v0 = ((const uint*)(feat + (size_t)r0 * HID))[c];
    uint v1 = ((const uint*)(feat + (size_t)r1 * HID))[c];
    uint v2 = ((const uint*)(feat + (size_t)r2 * HID))[c];
    uint v3 = ((const uint*)(feat + (size_t)r3 * HID))[c];
    float2 f0 = h2f2(v0), f1 = h2f2(v1), f2 = h2f2(v2), f3 = h2f2(v3);
    acc.x += (f0.x + f1.x) + (f2.x + f3.x);
    acc.y += (f0.y + f1.y) + (f2.y + f3.y);
  }
  for (; j < s1; ++j) {
    uint v = ((const uint*)(feat + (size_t)csr[j] * HID))[c];
    float2 f = h2f2(v);
    acc.x += f.x; acc.y += f.y;
  }
  float inv = 1.f / fmaxf((float)(s1 - s0), 1.f);
  __half2 o = __floats2half2_rn(acc.x * inv, acc.y * inv);
  ((uint*)(aggr + (size_t)node * HID))[c] = *reinterpret_cast<uint*>(&o);
}

// ---------- MFMA linear: C = A1@B1 + A2@B2 + bias, optional relu ----------
// A1,A2: [N,K] fp16. B*T: [NOUT][K] fp16 (transposed weights). C: [N,NOUT] fp16.
// Block = 4 waves; wave w handles rows [blk*64 + w*16, +16), all NOUT cols.
// B fragments preloaded to registers (fully unrolled, static indices).
template<int K, int NOUT, bool RELU>
__global__ __launch_bounds__(256) void k_lin_mfma(
    const __half* __restrict__ A1, const __half* __restrict__ A2,
    const __half* __restrict__ B1T, const __half* __restrict__ B2T,
    const float* __restrict__ bias, __half* __restrict__ Cout, int N) {
  constexpr int KS = K / 32;     // k-steps per operand
  constexpr int CT = NOUT / 16;  // col tiles
  const int lane = threadIdx.x & 63;
  const int wid = threadIdx.x >> 6;
  const int row0 = blockIdx.x * 64 + wid * 16;
  const int lr = lane & 15;      // row-in-tile for A, col-in-tile for B/C
  const int lk = (lane >> 4) * 8;  // k-chunk base

  // preload B fragments
  f16x8 b1[KS][CT], b2[KS][CT];
  #pragma unroll
  for (int t = 0; t < KS; ++t)
    #pragma unroll
    for (int ct = 0; ct < CT; ++ct) {
      const int c = ct * 16 + lr;
      b1[t][ct] = *(const f16x8*)((const _Float16*)B1T + (size_t)c * K + t * 32 + lk);
      b2[t][ct] = *(const f16x8*)((const _Float16*)B2T + (size_t)c * K + t * 32 + lk);
    }

  // init acc with bias (bias depends on col only)
  f32x4 acc[CT];
  #pragma unroll
  for (int ct = 0; ct < CT; ++ct) {
    float bv = bias[ct * 16 + lr];
    acc[ct] = (f32x4){bv, bv, bv, bv};
  }

  const int rA = min(row0 + lr, N - 1);
  const _Float16* a1p = (const _Float16*)A1 + (size_t)rA * K + lk;
  const _Float16* a2p = (const _Float16*)A2 + (size_t)rA * K + lk;
  #pragma unroll
  for (int t = 0; t < KS; ++t) {
    f16x8 a1 = *(const f16x8*)(a1p + t * 32);
    #pragma unroll
    for (int ct = 0; ct < CT; ++ct)
      acc[ct] = __builtin_amdgcn_mfma_f32_16x16x32_f16(a1, b1[t][ct], acc[ct], 0, 0, 0);
    f16x8 a2 = *(const f16x8*)(a2p + t * 32);
    #pragma unroll
    for (int ct = 0; ct < CT; ++ct)
      acc[ct] = __builtin_amdgcn_mfma_f32_16x16x32_f16(a2, b2[t][ct], acc[ct], 0, 0, 0);
  }

  // epilogue: C[row][col], col=ct*16+(lane&15), row=row0+(lane>>4)*4+r
  #pragma unroll
  for (int ct = 0; ct < CT; ++ct) {
    const int c = ct * 16 + lr;
    #pragma unroll
    for (int r = 0; r < 4; ++r) {
      const int row = row0 + (lane >> 4) * 4 + r;
      if (row < N) {
        float v = acc[ct][r];
        if (RELU) v = fmaxf(v, 0.f);
        Cout[(size_t)row * NOUT + c] = __float2half(v);
      }
    }
  }
}

// ---------- head precompute: gs = h2 @ Wp[0:64], gd = h2 @ Wp[64:128] ----------
__global__ __launch_bounds__(256) void k_headpre(const __half* __restrict__ h2,
    const float* __restrict__ Wp, float* __restrict__ gs, float* __restrict__ gd, int N) {
  __shared__ float sW[2 * OUTF];
  if (threadIdx.x < 2 * OUTF) sW[threadIdx.x] = Wp[threadIdx.x];
  __syncthreads();
  int n = blockIdx.x * 256 + threadIdx.x;
  if (n >= N) return;
  const uint4* row = (const uint4*)(h2 + (size_t)n * OUTF);
  float s = 0.f, d = 0.f;
  #pragma unroll
  for (int q = 0; q < 8; ++q) {
    uint4 v = row[q];
    float2 f0 = h2f2(v.x), f1 = h2f2(v.y), f2 = h2f2(v.z), f3 = h2f2(v.w);
    const float* w = sW + 8 * q;
    const float* w2 = sW + OUTF + 8 * q;
    s += f0.x * w[0] + f0.y * w[1] + f1.x * w[2] + f1.y * w[3]
       + f2.x * w[4] + f2.y * w[5] + f3.x * w[6] + f3.y * w[7];
    d += f0.x * w2[0] + f0.y * w2[1] + f1.x * w2[2] + f1.y * w2[3]
       + f2.x * w2[4] + f2.y * w2[5] + f3.x * w2[6] + f3.y * w2[7];
  }
  gs[n] = s; gd[n] = d;
}

// ---------- per-edge: raw = gs[src] + gd[dst] + bp; sigmoid ----------
__global__ __launch_bounds__(256) void k_edge(const float* __restrict__ gs,
    const float* __restrict__ gd, const int* __restrict__ srcI,
    const int* __restrict__ dstI, const float* __restrict__ bp,
    float* __restrict__ out, int E) {
  int e = blockIdx.x * 256 + threadIdx.x;
  if (e >= E) return;
  float raw = gs[srcI[e]] + gd[dstI[e]] + bp[0];
  out[e] = raw;
  out[(size_t)E + e] = 1.f / (1.f + expf(-raw));
}

extern "C" void kernel_launch(void* const* d_in, const int* in_sizes, int n_in,
                              void* d_out, int out_size, void* d_ws, size_t ws_size,
                              hipStream_t stream) {
  const float* x   = (const float*)d_in[0];
  const int*   ei  = (const int*)d_in[1];
  const float* W0  = (const float*)d_in[2];
  const float* b0  = (const float*)d_in[3];
  const float* W1l = (const float*)d_in[4];
  const float* b1l = (const float*)d_in[5];
  const float* W1r = (const float*)d_in[6];
  const float* W2l = (const float*)d_in[7];
  const float* b2l = (const float*)d_in[8];
  const float* W2r = (const float*)d_in[9];
  const float* Wp  = (const float*)d_in[10];
  const float* bp  = (const float*)d_in[11];

  const int N = in_sizes[0] / IN_X;
  const int E = in_sizes[1] / 2;
  const int* srcI = ei;
  const int* dstI = ei + E;
  float* out = (float*)d_out;

  // workspace layout
  __half* h0  = (__half*)d_ws;
  __half* ag1 = h0 + (size_t)N * IN_E;
  __half* h1  = ag1 + (size_t)N * IN_E;
  __half* ag2 = h1 + (size_t)N * HID;
  __half* h2  = ag2 + (size_t)N * HID;
  int* cnt     = (int*)(h2 + (size_t)N * OUTF);
  int* offs    = cnt + N;
  int* fillpos = offs + N + 1;
  int* csr     = fillpos + N;
  float* gs    = (float*)(csr + E);
  float* gd    = gs + N;
  uintptr_t wp = ((uintptr_t)(gd + N) + 15) & ~(uintptr_t)15;  // 16B align for f16x8
  __half* W1lT = (__half*)wp;
  __half* W1rT = W1lT + IN_E * HID;
  __half* W2lT = W1rT + IN_E * HID;
  __half* W2rT = W2lT + HID * OUTF;

  hipMemsetAsync(cnt, 0, sizeof(int) * (size_t)N, stream);
  hipMemsetAsync(fillpos, 0, sizeof(int) * (size_t)N, stream);

  k_prepw<<<32, 256, 0, stream>>>(W1l, W1r, W2l, W2r, W1lT, W1rT, W2lT, W2rT);
  // h0 = lin0(x)
  k_lin0<<<2048, 256, 0, stream>>>(x, W0, b0, h0, N);
  // CSR build
  k_count<<<(E + 255) / 256, 256, 0, stream>>>(dstI, cnt, E);
  k_scan<<<1, 1024, 0, stream>>>(cnt, offs, N);
  k_fill<<<(E + 255) / 256, 256, 0, stream>>>(srcI, dstI, offs, fillpos, csr, E);
  // conv1
  k_aggr64h<<<(N + 3) / 4, 256, 0, stream>>>(h0, csr, offs, ag1, N);
  k_lin_mfma<IN_E, HID, true><<<(N + 63) / 64, 256, 0, stream>>>(
      ag1, h0, W1lT, W1rT, b1l, h1, N);
  // conv2
  k_aggr128h<<<(N + 3) / 4, 256, 0, stream>>>(h1, csr, offs, ag2, N);
  k_lin_mfma<HID, OUTF, false><<<(N + 63) / 64, 256, 0, stream>>>(
      ag2, h1, W2lT, W2rT, b2l, h2, N);
  // edge head (separable)
  k_headpre<<<(N + 255) / 256, 256, 0, stream>>>(h2, Wp, gs, gd, N);
  k_edge<<<(E + 255) / 256, 256, 0, stream>>>(gs, gd, srcI, dstI, bp, out, E);
}